// Round 13
// baseline (302.702 us; speedup 1.0000x reference)
//
#include <hip/hip_runtime.h>
#include <cstddef>

#define NEG_INIT -1.0e9f

typedef _Float16 f16x8 __attribute__((ext_vector_type(8)));
typedef float f32x4 __attribute__((ext_vector_type(4)));

constexpr int D   = 512;   // feature dim
constexpr int BM  = 64;    // rows per block (halves Wfrag L2 traffic per row)
constexpr int BK  = 32;    // K per MFMA step
constexpr int NKS = D / BK;   // 16
constexpr int SSK = 4;     // K-steps per super-step (128 cols)
constexpr int NSS = NKS / SSK; // 4 super-steps
constexpr int LDH = 520;   // fp16 row stride (1040 B; proven ~conflict-free)
constexpr int PS  = 516;   // partial slot stride (floats): [m, s, pad, pad, f[512]]

// lgkm-only barrier: LDS producer/consumer safety WITHOUT draining vmcnt --
// in-flight global prefetches survive across it (counted-vmcnt pattern, T4).
#define BAR_LGKM()                                            \
    do {                                                      \
        asm volatile("s_waitcnt lgkmcnt(0)" ::: "memory");    \
        __builtin_amdgcn_s_barrier();                         \
        asm volatile("" ::: "memory");                        \
    } while (0)

// fast gates: v_exp_f32 + v_rcp_f32, inf-safe at both tails, err ~1e-6
__device__ __forceinline__ float fast_tanh(float v) {
    float e2 = __expf(2.f * v);
    return 1.f - 2.f * __builtin_amdgcn_rcpf(e2 + 1.f);
}
__device__ __forceinline__ float fast_sigmoid(float u) {
    return __builtin_amdgcn_rcpf(1.f + __expf(-u));
}

// ---------------------------------------------------------------------------
// k_wprep: fragment-major fp16 weights (unchanged layout).
//   Wfrag[(((quad*16 + ks)*4 + j)*64 + lane)*8 + e], j: 0,1 = V chunks, 2,3 = U.
// ---------------------------------------------------------------------------
__global__ __launch_bounds__(64) void k_wprep(const float* __restrict__ Vw,
                                              const float* __restrict__ Uw,
                                              _Float16* __restrict__ Wfrag) {
    const int bid  = blockIdx.x;
    const int lane = threadIdx.x;
    const int j    = bid & 3;
    const int ks   = (bid >> 2) & 15;
    const int wc   = bid >> 6;
    const int l15  = lane & 15;
    const int kgrp = lane >> 4;
    const float* src = (j < 2 ? Vw + (size_t)(wc * 32 + j * 16 + l15) * D
                              : Uw + (size_t)(wc * 32 + (j - 2) * 16 + l15) * D)
                       + ks * BK + kgrp * 8;
    f16x8 h;
    #pragma unroll
    for (int e = 0; e < 8; ++e) h[e] = (_Float16)src[e];
    *(f16x8*)(Wfrag + ((size_t)bid * 64 + lane) * 8) = h;
}

// ---------------------------------------------------------------------------
// k_bounds: start[g] = lower_bound(index, g), g in [0, G].
// ---------------------------------------------------------------------------
__global__ __launch_bounds__(256) void k_bounds(const int* __restrict__ index,
                                                int N, int G,
                                                int* __restrict__ start) {
    int g = blockIdx.x * blockDim.x + threadIdx.x;
    if (g > G) return;
    int lo = 0, hi = N;
    while (lo < hi) {
        int mid = (lo + hi) >> 1;
        if (index[mid] < g) lo = mid + 1; else hi = mid;
    }
    start[g] = lo;
}

// ---------------------------------------------------------------------------
// k_fused v13: BM=64, 512 threads, 8 waves -- wave wc owns att cols
// [wc*16, wc*16+16) (V and U) for ALL 64 rows (4 A-fragments, 8 MFMA/ks).
// Weight reads per block stay 256 KB -> per-row weight L2 traffic HALVES
// vs BM=32 (2.1 -> 1.05 GB total). R10's failure causes fixed: correct
// 1-wave-per-fragment assignment, Xh-only LDS (~69 KB -> 2 blocks/CU,
// 16 waves), VGPR cap 128 (no spill; live set ~115).
// Super-step pipeline (R9): per ss, issue ss+2 global loads (4x float4),
// compute 4 ks, commit ss+1 (cvt fp16, 2x b128), lgkm-only barrier.
// Pooling: exact fp32 re-read of the block's 64 rows from global (L2-hot;
// this CU streamed them moments earlier). feats HBM read happens ONCE;
// the pooling re-read is served by L2/L3.
// ---------------------------------------------------------------------------
__global__ __launch_bounds__(512, 4) void k_fused(
    const float* __restrict__ feats, const _Float16* __restrict__ Wfrag,
    const float* __restrict__ Vb, const float* __restrict__ Ub,
    const float* __restrict__ ww, const int* __restrict__ index,
    const int* __restrict__ start, float* __restrict__ P, int N)
{
    __shared__ __align__(16) _Float16 Xh[BM][LDH];      // 66560 B fp16 main
    __shared__ float sred[8][BM];                       //  2048 B
    __shared__ float srow[BM];
    __shared__ float evals[BM];

    const int t    = threadIdx.x;
    const int lane = t & 63;
    const int wc   = t >> 6;     // wave 0..7
    const int l15  = lane & 15;
    const int kgrp = lane >> 4;  // 0..3
    const int blk  = blockIdx.x;
    const int rb   = blk * BM;

    // staging map: thread t -> row t>>3 (0..63), 16-col chunk (t&7)*16 of
    // each 128-col super-step slab (512 threads x 16 floats = 64x128 exactly).
    const int srw  = t >> 3;
    const int scol = (t & 7) * 16;
    const float* xg = feats + (size_t)(rb + srw) * D + scol;

    float4 xa[2][4];                  // 2-superstep in-flight ring (32 VGPR)
    auto issueX = [&](int ss) {
        const float* p = xg + ss * 128;
        #pragma unroll
        for (int q = 0; q < 4; ++q)
            xa[ss & 1][q] = *(const float4*)(p + q * 4);
    };
    auto commitX = [&](int ss) {
        const int c0 = ss * 128 + scol;
        #pragma unroll
        for (int half = 0; half < 2; ++half) {
            float4 a = xa[ss & 1][half * 2], b = xa[ss & 1][half * 2 + 1];
            f16x8 h = { (_Float16)a.x, (_Float16)a.y, (_Float16)a.z, (_Float16)a.w,
                        (_Float16)b.x, (_Float16)b.y, (_Float16)b.z, (_Float16)b.w };
            *(f16x8*)&Xh[srw][c0 + half * 8] = h;
        }
    };

    // per-(wc,lane) base into fragment-major weights (same as R9: wave wc ->
    // quad wc>>1, V chunk wc&1, U chunk 2+(wc&1))
    const _Float16* wbV = Wfrag + (size_t)(wc >> 1) * 32768
                                + (size_t)(wc & 1) * 512 + (size_t)lane * 8;
    const _Float16* wbU = wbV + 1024;

    f32x4 accV[4], accU[4];
    #pragma unroll
    for (int i = 0; i < 4; ++i) {
        accV[i] = (f32x4){0.f, 0.f, 0.f, 0.f};
        accU[i] = (f32x4){0.f, 0.f, 0.f, 0.f};
    }

    // ---- pipelined stage + K-loop ----
    issueX(0); issueX(1);
    commitX(0);
    BAR_LGKM();

    #pragma unroll
    for (int ss = 0; ss < NSS; ++ss) {
        if (ss + 2 < NSS) issueX(ss + 2);     // HBM loads 2 super-steps ahead
        #pragma unroll
        for (int k2 = 0; k2 < SSK; ++k2) {
            const int ks = ss * SSK + k2;
            f16x8 bv = *(const f16x8*)(wbV + (size_t)ks * 2048);
            f16x8 bu = *(const f16x8*)(wbU + (size_t)ks * 2048);
            f16x8 ha[4];
            #pragma unroll
            for (int i = 0; i < 4; ++i)
                ha[i] = *(const f16x8*)&Xh[i * 16 + l15][ks * BK + kgrp * 8];
            #pragma unroll
            for (int i = 0; i < 4; ++i) {
                accV[i] = __builtin_amdgcn_mfma_f32_16x16x32_f16(ha[i], bv, accV[i], 0, 0, 0);
                accU[i] = __builtin_amdgcn_mfma_f32_16x16x32_f16(ha[i], bu, accU[i], 0, 0, 0);
            }
        }
        if (ss + 1 < NSS) {
            commitX(ss + 1);                  // counted vmcnt wait on xa only
            BAR_LGKM();
        }
    }

    // ---- gated epilogue -> per-row scores (fast exp/rcp gates) ----
    {
        const int c = wc * 16 + l15;          // attention col 0..127
        const float vb = Vb[c], ub = Ub[c], w = ww[c];
        float part[4][4];
        #pragma unroll
        for (int i = 0; i < 4; ++i)
            #pragma unroll
            for (int r = 0; r < 4; ++r) {
                float v = accV[i][r] + vb;
                float u = accU[i][r] + ub;
                part[i][r] = w * fast_tanh(v) * fast_sigmoid(u);
            }
        #pragma unroll
        for (int off = 1; off < 16; off <<= 1)
            #pragma unroll
            for (int i = 0; i < 4; ++i)
                #pragma unroll
                for (int r = 0; r < 4; ++r)
                    part[i][r] += __shfl_xor(part[i][r], off);
        if (l15 == 0) {
            #pragma unroll
            for (int i = 0; i < 4; ++i)
                #pragma unroll
                for (int r = 0; r < 4; ++r)
                    sred[wc][i * 16 + kgrp * 4 + r] = part[i][r];
        }
    }
    __syncthreads();
    if (t < BM) {
        float s = sred[0][t];
        #pragma unroll
        for (int w8 = 1; w8 < 8; ++w8) s += sred[w8][t];
        srow[t] = s;
    }
    __syncthreads();

    // ---- wave-parallel per-segment softmax partials ----
    const int gl = index[rb];
    const int gh = index[rb + BM - 1];
    for (int g = gl + wc; g <= gh; g += 8) {
        const int r0 = max(start[g], rb), r1 = min(start[g + 1], rb + BM);
        if (r1 <= r0) continue;
        const bool in = (lane >= r0 - rb) && (lane < r1 - rb);
        float m = in ? srow[lane] : NEG_INIT;
        #pragma unroll
        for (int off = 32; off; off >>= 1) m = fmaxf(m, __shfl_xor(m, off));
        float e = in ? __expf(srow[lane] - m) : 0.f;
        if (in) evals[lane] = e;
        float s = e;
        #pragma unroll
        for (int off = 32; off; off >>= 1) s += __shfl_xor(s, off);
        if (lane == 0) {
            float* slot = P + (size_t)(blk + g) * PS;
            slot[0] = m; slot[1] = s;
        }
    }
    __syncthreads();

    // ---- pooling partials: exact fp32 re-read of the block's rows from
    //      global (L2-hot), 1 col/thread across all 512 threads ----
    {
        for (int g = gl; g <= gh; ++g) {
            const int r0 = max(start[g], rb), r1 = min(start[g + 1], rb + BM);
            if (r1 <= r0) continue;
            float a = 0.f;
            for (int r = r0; r < r1; ++r) {
                const float e = evals[r - rb];                 // LDS broadcast
                float x = feats[(size_t)r * D + t];            // L2-hot global
                a = fmaf(e, x, a);
            }
            P[(size_t)(blk + g) * PS + 4 + t] = a;
        }
    }
}

// ---------------------------------------------------------------------------
// k_merge: combine per-block segment partials; one block per group, t = col.
// ---------------------------------------------------------------------------
__global__ __launch_bounds__(512) void k_merge(const float* __restrict__ P,
                                               const int* __restrict__ start,
                                               float* __restrict__ out)
{
    const int g = blockIdx.x, t = threadIdx.x;
    const int s0 = start[g], s1 = start[g + 1];
    if (s0 >= s1) { out[(size_t)g * D + t] = 0.f; return; }
    const int b0 = s0 >> 6, b1 = (s1 - 1) >> 6;   // BM = 64
    float M = NEG_INIT;
    for (int b = b0; b <= b1; ++b)
        M = fmaxf(M, P[(size_t)(b + g) * PS]);
    float den = 0.f, acc = 0.f;
    for (int b = b0; b <= b1; ++b) {
        const float* slot = P + (size_t)(b + g) * PS;
        float w = __expf(slot[0] - M);
        den += w * slot[1];
        acc += w * slot[4 + t];
    }
    out[(size_t)g * D + t] = acc / (den + 1e-8f);
}

// ---------------------------------------------------------------------------
extern "C" void kernel_launch(void* const* d_in, const int* in_sizes, int n_in,
                              void* d_out, int out_size, void* d_ws, size_t ws_size,
                              hipStream_t stream) {
    const float* feats = (const float*)d_in[0];
    const int*   index = (const int*)d_in[1];
    const float* Vw = (const float*)d_in[3];
    const float* Vb = (const float*)d_in[4];
    const float* Uw = (const float*)d_in[5];
    const float* Ub = (const float*)d_in[6];
    const float* ww = (const float*)d_in[7];
    float* out = (float*)d_out;

    const int N = in_sizes[1];          // 262144
    const int G = out_size / D;         // 512
    const int nblk = (N + BM - 1) / BM; // 4096

    // ws: Wfrag fp16[256*512] | start[G+1] | (16B align) | P[(nblk+G)*PS]
    _Float16* Wfrag = (_Float16*)d_ws;
    int* start      = (int*)(Wfrag + (size_t)256 * 512);
    size_t off      = (size_t)256 * 512 * 2 + (G + 1) * 4;
    off             = (off + 15) & ~(size_t)15;
    float* P        = (float*)((char*)d_ws + off);

    hipLaunchKernelGGL(k_wprep, dim3(256), dim3(64), 0, stream, Vw, Uw, Wfrag);
    hipLaunchKernelGGL(k_bounds, dim3((G + 1 + 255) / 256), dim3(256), 0, stream,
                       index, N, G, start);
    hipLaunchKernelGGL(k_fused, dim3(nblk), dim3(512), 0, stream,
                       feats, Wfrag, Vb, Ub, ww, index, start, P, N);
    hipLaunchKernelGGL(k_merge, dim3(G), dim3(512), 0, stream, P, start, out);
}

// Round 14
// 213.560 us; speedup vs baseline: 1.4174x; 1.4174x over previous
//
#include <hip/hip_runtime.h>
#include <hip/hip_fp8.h>
#include <cstddef>

#define NEG_INIT -1.0e9f

typedef _Float16 f16x8 __attribute__((ext_vector_type(8)));
typedef float f32x4 __attribute__((ext_vector_type(4)));

constexpr int D   = 512;   // feature dim
constexpr int BM  = 32;    // rows per block
constexpr int BK  = 32;    // K per MFMA step
constexpr int NKS = D / BK;   // 16
constexpr int SSK = 4;     // K-steps per super-step (128 cols)
constexpr int NSS = NKS / SSK; // 4 super-steps
constexpr int LDH  = 520;  // fp16 row stride (1040 B)
constexpr int LDRB = 520;  // fp8 residual row stride BYTES
constexpr int PS  = 516;   // partial slot stride (floats): [m, s, pad, pad, f[512]]
constexpr float RSC  = 2048.f;      // residual scale into fp8 range
constexpr float RISC = 1.f / 2048.f;

// lgkm-only barrier: LDS producer/consumer safety WITHOUT draining vmcnt --
// in-flight global prefetches survive across it (counted-vmcnt pattern, T4).
#define BAR_LGKM()                                            \
    do {                                                      \
        asm volatile("s_waitcnt lgkmcnt(0)" ::: "memory");    \
        __builtin_amdgcn_s_barrier();                         \
        asm volatile("" ::: "memory");                        \
    } while (0)

#if __has_builtin(__builtin_amdgcn_cvt_pk_fp8_f32) && __has_builtin(__builtin_amdgcn_cvt_f32_fp8)
#define HW_FP8 1
#else
#define HW_FP8 0
#endif

__device__ __forceinline__ unsigned int pack_fp8x4(float r0, float r1,
                                                   float r2, float r3) {
#if HW_FP8
    int p = __builtin_amdgcn_cvt_pk_fp8_f32(r0, r1, 0, false);   // bytes 0,1
    p     = __builtin_amdgcn_cvt_pk_fp8_f32(r2, r3, p, true);    // bytes 2,3
    return (unsigned int)p;
#else
    __hip_fp8_e4m3 q0(r0), q1(r1), q2(r2), q3(r3);
    return (unsigned int)q0.__x | ((unsigned int)q1.__x << 8) |
           ((unsigned int)q2.__x << 16) | ((unsigned int)q3.__x << 24);
#endif
}

template <int SEL>
__device__ __forceinline__ float unpack_fp8(unsigned int word) {
#if HW_FP8
    return __builtin_amdgcn_cvt_f32_fp8((int)word, SEL);
#else
    __hip_fp8_e4m3 q;
    q.__x = (unsigned char)(word >> (8 * SEL));
    return (float)q;
#endif
}

// fast gates: v_exp_f32 + v_rcp_f32, inf-safe at both tails, err ~1e-6
__device__ __forceinline__ float fast_tanh(float v) {
    float e2 = __expf(2.f * v);
    return 1.f - 2.f * __builtin_amdgcn_rcpf(e2 + 1.f);
}
__device__ __forceinline__ float fast_sigmoid(float u) {
    return __builtin_amdgcn_rcpf(1.f + __expf(-u));
}

// ---------------------------------------------------------------------------
// k_wprep: fragment-major fp16 weights (unchanged layout).
// ---------------------------------------------------------------------------
__global__ __launch_bounds__(64) void k_wprep(const float* __restrict__ Vw,
                                              const float* __restrict__ Uw,
                                              _Float16* __restrict__ Wfrag) {
    const int bid  = blockIdx.x;
    const int lane = threadIdx.x;
    const int j    = bid & 3;
    const int ks   = (bid >> 2) & 15;
    const int wc   = bid >> 6;
    const int l15  = lane & 15;
    const int kgrp = lane >> 4;
    const float* src = (j < 2 ? Vw + (size_t)(wc * 32 + j * 16 + l15) * D
                              : Uw + (size_t)(wc * 32 + (j - 2) * 16 + l15) * D)
                       + ks * BK + kgrp * 8;
    f16x8 h;
    #pragma unroll
    for (int e = 0; e < 8; ++e) h[e] = (_Float16)src[e];
    *(f16x8*)(Wfrag + ((size_t)bid * 64 + lane) * 8) = h;
}

// ---------------------------------------------------------------------------
// k_bounds: start[g] = lower_bound(index, g), g in [0, G].
// ---------------------------------------------------------------------------
__global__ __launch_bounds__(256) void k_bounds(const int* __restrict__ index,
                                                int N, int G,
                                                int* __restrict__ start) {
    int g = blockIdx.x * blockDim.x + threadIdx.x;
    if (g > G) return;
    int lo = 0, hi = N;
    while (lo < hi) {
        int mid = (lo + hi) >> 1;
        if (index[mid] < g) lo = mid + 1; else hi = mid;
    }
    start[g] = lo;
}

// ---------------------------------------------------------------------------
// k_fused v14 = R12 base with the super-step VMEM issue ORDER fixed.
// vmcnt is a single in-order counter per wave: in R9/R12 the HBM prefetch
// (issueX, ~900 cyc) was issued BEFORE the super-step's Wfrag L2 loads, so
// every wait on a weight fragment also drained the fresh HBM load. v14
// batches ALL 8 B-fragments of the super-step into registers FIRST, then
// issues the X prefetch (sched_barrier(0) pins the order). Waiting on bf
// now leaves only the newer xa outstanding; xa completes under the MFMA
// phase. Prefetch depth 1 (xa single-buffer) to fit the bf batch in the
// 85-VGPR cap (live ~84). Everything else identical to R12: BM=32, 8
// waves, 3 blocks/CU, fp16 Xh + fp8 residual, lgkm-only barriers, fast
// gates, 1-col/thread pooling.
// ---------------------------------------------------------------------------
__global__ __launch_bounds__(512, 6) void k_fused(
    const float* __restrict__ feats, const _Float16* __restrict__ Wfrag,
    const float* __restrict__ Vb, const float* __restrict__ Ub,
    const float* __restrict__ ww, const int* __restrict__ index,
    const int* __restrict__ start, float* __restrict__ P, int N)
{
    __shared__ __align__(16) _Float16 Xh[BM][LDH];         // 33280 B fp16 main
    __shared__ __align__(8)  unsigned char Xr8[BM * LDRB]; // 16640 B fp8 residual
    __shared__ float sred[8][BM];                          //  1024 B
    __shared__ float srow[BM];
    __shared__ float evals[BM];

    const int t    = threadIdx.x;
    const int lane = t & 63;
    const int wc   = t >> 6;     // wave 0..7
    const int l15  = lane & 15;
    const int kgrp = lane >> 4;  // 0..3
    const int blk  = blockIdx.x;
    const int rb   = blk * BM;

    // staging map: thread t -> row t>>4, 8-col chunk (t&15)*8 of each 128-col
    // super-step slab (512 threads cover 32x128 exactly).
    const int srw  = t >> 4;          // 0..31
    const int scol = (t & 15) * 8;    // 0..120
    const float* xg = feats + (size_t)(rb + srw) * D + scol;

    float4 xa0, xa1;                  // single-superstep staging regs (8 VGPR)
    auto issueX = [&](int ss) {
        const float* p = xg + ss * 128;
        xa0 = *(const float4*)p;
        xa1 = *(const float4*)(p + 4);
    };
    auto commitX = [&](int ss) {
        const int c0 = ss * 128 + scol;
        float v[8];
        v[0] = xa0.x; v[1] = xa0.y; v[2] = xa0.z; v[3] = xa0.w;
        v[4] = xa1.x; v[5] = xa1.y; v[6] = xa1.z; v[7] = xa1.w;
        f16x8 h;
        float res[8];
        #pragma unroll
        for (int e = 0; e < 8; ++e) {
            h[e] = (_Float16)v[e];
            res[e] = (v[e] - (float)h[e]) * RSC;
        }
        unsigned int rp0 = pack_fp8x4(res[0], res[1], res[2], res[3]);
        unsigned int rp1 = pack_fp8x4(res[4], res[5], res[6], res[7]);
        *(f16x8*)&Xh[srw][c0] = h;
        uint2 rw = {rp0, rp1};
        *(uint2*)&Xr8[srw * LDRB + c0] = rw;
    };

    // per-(wc,lane) base into fragment-major weights
    const _Float16* wbV = Wfrag + (size_t)(wc >> 1) * 32768
                                + (size_t)(wc & 1) * 512 + (size_t)lane * 8;
    const _Float16* wbU = wbV + 1024;

    f32x4 accV[2], accU[2];
    #pragma unroll
    for (int i = 0; i < 2; ++i) {
        accV[i] = (f32x4){0.f, 0.f, 0.f, 0.f};
        accU[i] = (f32x4){0.f, 0.f, 0.f, 0.f};
    }

    // ---- pipelined stage + K-loop (issue order: bf batch -> xa) ----
    issueX(0);
    commitX(0);                        // one exposed HBM wait (prologue only)
    BAR_LGKM();

    #pragma unroll
    for (int ss = 0; ss < NSS; ++ss) {
        // 1) batch-load ALL B fragments of this super-step into registers
        f16x8 bv[SSK], bu[SSK];
        #pragma unroll
        for (int k2 = 0; k2 < SSK; ++k2) {
            const int ks = ss * SSK + k2;
            bv[k2] = *(const f16x8*)(wbV + (size_t)ks * 2048);
            bu[k2] = *(const f16x8*)(wbU + (size_t)ks * 2048);
        }
        __builtin_amdgcn_sched_barrier(0);   // keep xa issue AFTER bf issue
        // 2) issue next super-step's HBM loads (newest in the vmcnt queue)
        if (ss + 1 < NSS) issueX(ss + 1);
        __builtin_amdgcn_sched_barrier(0);
        // 3) MFMA phase: waits on bf leave xa outstanding (counted vmcnt)
        #pragma unroll
        for (int k2 = 0; k2 < SSK; ++k2) {
            const int ks = ss * SSK + k2;
            f16x8 ha[2];
            #pragma unroll
            for (int i = 0; i < 2; ++i)
                ha[i] = *(const f16x8*)&Xh[i * 16 + l15][ks * BK + kgrp * 8];
            #pragma unroll
            for (int i = 0; i < 2; ++i) {
                accV[i] = __builtin_amdgcn_mfma_f32_16x16x32_f16(ha[i], bv[k2], accV[i], 0, 0, 0);
                accU[i] = __builtin_amdgcn_mfma_f32_16x16x32_f16(ha[i], bu[k2], accU[i], 0, 0, 0);
            }
        }
        // 4) commit next tile (waits xa, which has had the MFMA phase to land)
        if (ss + 1 < NSS) {
            commitX(ss + 1);
            BAR_LGKM();
        }
    }

    // ---- gated epilogue -> per-row scores (fast exp/rcp gates) ----
    {
        const int c = wc * 16 + l15;          // attention col 0..127
        const float vb = Vb[c], ub = Ub[c], w = ww[c];
        float part[2][4];
        #pragma unroll
        for (int i = 0; i < 2; ++i)
            #pragma unroll
            for (int r = 0; r < 4; ++r) {
                float v = accV[i][r] + vb;
                float u = accU[i][r] + ub;
                part[i][r] = w * fast_tanh(v) * fast_sigmoid(u);
            }
        #pragma unroll
        for (int off = 1; off < 16; off <<= 1)
            #pragma unroll
            for (int i = 0; i < 2; ++i)
                #pragma unroll
                for (int r = 0; r < 4; ++r)
                    part[i][r] += __shfl_xor(part[i][r], off);
        if (l15 == 0) {
            #pragma unroll
            for (int i = 0; i < 2; ++i)
                #pragma unroll
                for (int r = 0; r < 4; ++r)
                    sred[wc][i * 16 + kgrp * 4 + r] = part[i][r];
        }
    }
    __syncthreads();
    if (t < BM) {
        float s = sred[0][t];
        #pragma unroll
        for (int w8 = 1; w8 < 8; ++w8) s += sred[w8][t];
        srow[t] = s;
    }
    __syncthreads();

    // ---- wave-parallel per-segment softmax partials ----
    const int gl = index[rb];
    const int gh = index[rb + BM - 1];
    for (int g = gl + wc; g <= gh; g += 8) {
        const int r0 = max(start[g], rb), r1 = min(start[g + 1], rb + BM);
        if (r1 <= r0) continue;
        const bool in = (lane >= r0 - rb) && (lane < r1 - rb);
        float m = in ? srow[lane] : NEG_INIT;
        #pragma unroll
        for (int off = 32; off; off >>= 1) m = fmaxf(m, __shfl_xor(m, off));
        float e = in ? __expf(srow[lane] - m) : 0.f;
        if (in) evals[lane] = e;
        float s = e;
        #pragma unroll
        for (int off = 32; off; off >>= 1) s += __shfl_xor(s, off);
        if (lane == 0) {
            float* slot = P + (size_t)(blk + g) * PS;
            slot[0] = m; slot[1] = s;
        }
    }
    __syncthreads();

    // ---- pooling partials: 1 col/thread, all 512 threads ----
    {
        for (int g = gl; g <= gh; ++g) {
            const int r0 = max(start[g], rb), r1 = min(start[g + 1], rb + BM);
            if (r1 <= r0) continue;
            float a = 0.f;
            for (int r = r0; r < r1; ++r) {
                const int rr = r - rb;
                float h = (float)Xh[rr][t];
                unsigned int rv = Xr8[rr * LDRB + t];
                float x = fmaf(unpack_fp8<0>(rv), RISC, h);
                a = fmaf(evals[rr], x, a);
            }
            P[(size_t)(blk + g) * PS + 4 + t] = a;
        }
    }
}

// ---------------------------------------------------------------------------
// k_merge: combine per-block segment partials; one block per group, t = col.
// ---------------------------------------------------------------------------
__global__ __launch_bounds__(512) void k_merge(const float* __restrict__ P,
                                               const int* __restrict__ start,
                                               float* __restrict__ out)
{
    const int g = blockIdx.x, t = threadIdx.x;
    const int s0 = start[g], s1 = start[g + 1];
    if (s0 >= s1) { out[(size_t)g * D + t] = 0.f; return; }
    const int b0 = s0 >> 5, b1 = (s1 - 1) >> 5;   // BM = 32
    float M = NEG_INIT;
    for (int b = b0; b <= b1; ++b)
        M = fmaxf(M, P[(size_t)(b + g) * PS]);
    float den = 0.f, acc = 0.f;
    for (int b = b0; b <= b1; ++b) {
        const float* slot = P + (size_t)(b + g) * PS;
        float w = __expf(slot[0] - M);
        den += w * slot[1];
        acc += w * slot[4 + t];
    }
    out[(size_t)g * D + t] = acc / (den + 1e-8f);
}

// ---------------------------------------------------------------------------
extern "C" void kernel_launch(void* const* d_in, const int* in_sizes, int n_in,
                              void* d_out, int out_size, void* d_ws, size_t ws_size,
                              hipStream_t stream) {
    const float* feats = (const float*)d_in[0];
    const int*   index = (const int*)d_in[1];
    const float* Vw = (const float*)d_in[3];
    const float* Vb = (const float*)d_in[4];
    const float* Uw = (const float*)d_in[5];
    const float* Ub = (const float*)d_in[6];
    const float* ww = (const float*)d_in[7];
    float* out = (float*)d_out;

    const int N = in_sizes[1];          // 262144
    const int G = out_size / D;         // 512
    const int nblk = (N + BM - 1) / BM; // 8192

    // ws: Wfrag fp16[256*512] | start[G+1] | (16B align) | P[(nblk+G)*PS]
    _Float16* Wfrag = (_Float16*)d_ws;
    int* start      = (int*)(Wfrag + (size_t)256 * 512);
    size_t off      = (size_t)256 * 512 * 2 + (G + 1) * 4;
    off             = (off + 15) & ~(size_t)15;
    float* P        = (float*)((char*)d_ws + off);

    hipLaunchKernelGGL(k_wprep, dim3(256), dim3(64), 0, stream, Vw, Uw, Wfrag);
    hipLaunchKernelGGL(k_bounds, dim3((G + 1 + 255) / 256), dim3(256), 0, stream,
                       index, N, G, start);
    hipLaunchKernelGGL(k_fused, dim3(nblk), dim3(512), 0, stream,
                       feats, Wfrag, Vb, Ub, ww, index, start, P, N);
    hipLaunchKernelGGL(k_merge, dim3(G), dim3(512), 0, stream, P, start, out);
}

// Round 15
// 211.820 us; speedup vs baseline: 1.4291x; 1.0082x over previous
//
#include <hip/hip_runtime.h>
#include <hip/hip_fp8.h>
#include <cstddef>

#define NEG_INIT -1.0e9f

typedef _Float16 f16x8 __attribute__((ext_vector_type(8)));
typedef _Float16 f16x4 __attribute__((ext_vector_type(4)));
typedef _Float16 f16x2 __attribute__((ext_vector_type(2)));
typedef float f32x4 __attribute__((ext_vector_type(4)));

constexpr int D   = 512;   // feature dim
constexpr int BM  = 32;    // rows per block
constexpr int BK  = 32;    // K per MFMA step
constexpr int NKS = D / BK;   // 16
constexpr int SSK = 4;     // K-steps per super-step (128 cols)
constexpr int NSS = NKS / SSK; // 4 super-steps
constexpr int LDH  = 520;  // fp16 row stride (1040 B)
constexpr int LDRB = 520;  // fp8 residual row stride BYTES
constexpr int PS  = 516;   // partial slot stride (floats): [m, s, pad, pad, f[512]]
constexpr float RSC  = 2048.f;      // residual scale into fp8 range
constexpr float RISC = 1.f / 2048.f;

// lgkm-only barrier: LDS producer/consumer safety WITHOUT draining vmcnt --
// in-flight global prefetches survive across it (counted-vmcnt pattern, T4).
#define BAR_LGKM()                                            \
    do {                                                      \
        asm volatile("s_waitcnt lgkmcnt(0)" ::: "memory");    \
        __builtin_amdgcn_s_barrier();                         \
        asm volatile("" ::: "memory");                        \
    } while (0)

#if __has_builtin(__builtin_amdgcn_cvt_pk_fp8_f32) && __has_builtin(__builtin_amdgcn_cvt_f32_fp8)
#define HW_FP8 1
#else
#define HW_FP8 0
#endif

__device__ __forceinline__ unsigned int pack_fp8x4(float r0, float r1,
                                                   float r2, float r3) {
#if HW_FP8
    int p = __builtin_amdgcn_cvt_pk_fp8_f32(r0, r1, 0, false);   // bytes 0,1
    p     = __builtin_amdgcn_cvt_pk_fp8_f32(r2, r3, p, true);    // bytes 2,3
    return (unsigned int)p;
#else
    __hip_fp8_e4m3 q0(r0), q1(r1), q2(r2), q3(r3);
    return (unsigned int)q0.__x | ((unsigned int)q1.__x << 8) |
           ((unsigned int)q2.__x << 16) | ((unsigned int)q3.__x << 24);
#endif
}

template <int SEL>
__device__ __forceinline__ float unpack_fp8(unsigned int word) {
#if HW_FP8
    return __builtin_amdgcn_cvt_f32_fp8((int)word, SEL);
#else
    __hip_fp8_e4m3 q;
    q.__x = (unsigned char)(word >> (8 * SEL));
    return (float)q;
#endif
}

// fast gates: v_exp_f32 + v_rcp_f32, inf-safe at both tails, err ~1e-6
__device__ __forceinline__ float fast_tanh(float v) {
    float e2 = __expf(2.f * v);
    return 1.f - 2.f * __builtin_amdgcn_rcpf(e2 + 1.f);
}
__device__ __forceinline__ float fast_sigmoid(float u) {
    return __builtin_amdgcn_rcpf(1.f + __expf(-u));
}

// ---------------------------------------------------------------------------
// k_wprep: fragment-major fp16 weights (unchanged layout).
// ---------------------------------------------------------------------------
__global__ __launch_bounds__(64) void k_wprep(const float* __restrict__ Vw,
                                              const float* __restrict__ Uw,
                                              _Float16* __restrict__ Wfrag) {
    const int bid  = blockIdx.x;
    const int lane = threadIdx.x;
    const int j    = bid & 3;
    const int ks   = (bid >> 2) & 15;
    const int wc   = bid >> 6;
    const int l15  = lane & 15;
    const int kgrp = lane >> 4;
    const float* src = (j < 2 ? Vw + (size_t)(wc * 32 + j * 16 + l15) * D
                              : Uw + (size_t)(wc * 32 + (j - 2) * 16 + l15) * D)
                       + ks * BK + kgrp * 8;
    f16x8 h;
    #pragma unroll
    for (int e = 0; e < 8; ++e) h[e] = (_Float16)src[e];
    *(f16x8*)(Wfrag + ((size_t)bid * 64 + lane) * 8) = h;
}

// ---------------------------------------------------------------------------
// k_bounds: start[g] = lower_bound(index, g), g in [0, G].
// ---------------------------------------------------------------------------
__global__ __launch_bounds__(256) void k_bounds(const int* __restrict__ index,
                                                int N, int G,
                                                int* __restrict__ start) {
    int g = blockIdx.x * blockDim.x + threadIdx.x;
    if (g > G) return;
    int lo = 0, hi = N;
    while (lo < hi) {
        int mid = (lo + hi) >> 1;
        if (index[mid] < g) lo = mid + 1; else hi = mid;
    }
    start[g] = lo;
}

// ---------------------------------------------------------------------------
// k_fused v15 = R9 (best, 206.9 us) + PER-BLOCK SUPER-STEP ROTATION.
// Co-resident blocks previously ran identical schedules, so their HBM
// staging bursts and Wfrag-L2 bursts collided on the same memory pipes
// each phase. GEMM accumulation is K-order independent, so block blk
// processes K-slabs in rotated order (rot + i) & 3, rot = blk & 3:
// neighboring blocks on a CU stage different slabs and read different
// 64 KB Wfrag regions at any instant -> phases interleave instead of
// colliding. Everything else is the verified R9 structure: BM=32,
// 512 thr / 8 waves, 3 blocks/CU (LDS 50 KB, (512,6)), super-step
// pipeline with 2-deep reg ring, fp16 Xh + fp8 residual Xr8, lgkm-only
// barriers, fast gates, 2-col/256-thread pooling. feats read ONCE.
// ---------------------------------------------------------------------------
__global__ __launch_bounds__(512, 6) void k_fused(
    const float* __restrict__ feats, const _Float16* __restrict__ Wfrag,
    const float* __restrict__ Vb, const float* __restrict__ Ub,
    const float* __restrict__ ww, const int* __restrict__ index,
    const int* __restrict__ start, float* __restrict__ P, int N)
{
    __shared__ __align__(16) _Float16 Xh[BM][LDH];         // 33280 B fp16 main
    __shared__ __align__(8)  unsigned char Xr8[BM * LDRB]; // 16640 B fp8 residual
    __shared__ float sred[8][BM];                          //  1024 B
    __shared__ float srow[BM];
    __shared__ float evals[BM];

    const int t    = threadIdx.x;
    const int lane = t & 63;
    const int wc   = t >> 6;     // wave 0..7
    const int l15  = lane & 15;
    const int kgrp = lane >> 4;  // 0..3
    const int blk  = blockIdx.x;
    const int rb   = blk * BM;
    const int rot  = blk & 3;    // per-block K-slab rotation

    // staging map: thread t -> row t>>4, 8-col chunk (t&15)*8 of each 128-col
    // super-step slab (512 threads cover 32x128 exactly).
    const int srw  = t >> 4;          // 0..31
    const int scol = (t & 15) * 8;    // 0..120
    const float* xg = feats + (size_t)(rb + srw) * D + scol;

    float4 xa[2][2];                  // 2-position in-flight ring (16 VGPR)
    // position i in the rotated sequence -> slab (rot+i)&3
    auto issueX = [&](int i) {
        const int slab = (rot + i) & 3;
        const float* p = xg + slab * 128;
        xa[i & 1][0] = *(const float4*)p;
        xa[i & 1][1] = *(const float4*)(p + 4);
    };
    auto commitX = [&](int i) {
        const int slab = (rot + i) & 3;
        const int c0 = slab * 128 + scol;
        float v[8];
        v[0] = xa[i & 1][0].x; v[1] = xa[i & 1][0].y;
        v[2] = xa[i & 1][0].z; v[3] = xa[i & 1][0].w;
        v[4] = xa[i & 1][1].x; v[5] = xa[i & 1][1].y;
        v[6] = xa[i & 1][1].z; v[7] = xa[i & 1][1].w;
        f16x8 h;
        float res[8];
        #pragma unroll
        for (int e = 0; e < 8; ++e) {
            h[e] = (_Float16)v[e];
            res[e] = (v[e] - (float)h[e]) * RSC;
        }
        unsigned int rp0 = pack_fp8x4(res[0], res[1], res[2], res[3]);
        unsigned int rp1 = pack_fp8x4(res[4], res[5], res[6], res[7]);
        *(f16x8*)&Xh[srw][c0] = h;
        uint2 rw = {rp0, rp1};
        *(uint2*)&Xr8[srw * LDRB + c0] = rw;
    };

    // per-(wc,lane) base into fragment-major weights
    const _Float16* wbV = Wfrag + (size_t)(wc >> 1) * 32768
                                + (size_t)(wc & 1) * 512 + (size_t)lane * 8;
    const _Float16* wbU = wbV + 1024;

    f32x4 accV[2], accU[2];
    #pragma unroll
    for (int i = 0; i < 2; ++i) {
        accV[i] = (f32x4){0.f, 0.f, 0.f, 0.f};
        accU[i] = (f32x4){0.f, 0.f, 0.f, 0.f};
    }

    // ---- pipelined stage + K-loop (rotated slab order) ----
    issueX(0); issueX(1);
    commitX(0);
    BAR_LGKM();

    #pragma unroll
    for (int i = 0; i < NSS; ++i) {
        if (i + 2 < NSS) issueX(i + 2);       // HBM loads 2 positions ahead
        const int slab = (rot + i) & 3;
        #pragma unroll
        for (int k2 = 0; k2 < SSK; ++k2) {
            const int ks = slab * SSK + k2;
            f16x8 bv = *(const f16x8*)(wbV + (size_t)ks * 2048);
            f16x8 bu = *(const f16x8*)(wbU + (size_t)ks * 2048);
            f16x8 ha[2];
            #pragma unroll
            for (int q = 0; q < 2; ++q)
                ha[q] = *(const f16x8*)&Xh[q * 16 + l15][ks * BK + kgrp * 8];
            #pragma unroll
            for (int q = 0; q < 2; ++q) {
                accV[q] = __builtin_amdgcn_mfma_f32_16x16x32_f16(ha[q], bv, accV[q], 0, 0, 0);
                accU[q] = __builtin_amdgcn_mfma_f32_16x16x32_f16(ha[q], bu, accU[q], 0, 0, 0);
            }
        }
        if (i + 1 < NSS) {
            commitX(i + 1);                   // counted vmcnt wait on xa only
            BAR_LGKM();
        }
    }

    // ---- gated epilogue -> per-row scores (fast exp/rcp gates) ----
    {
        const int c = wc * 16 + l15;          // attention col 0..127
        const float vb = Vb[c], ub = Ub[c], w = ww[c];
        float part[2][4];
        #pragma unroll
        for (int i = 0; i < 2; ++i)
            #pragma unroll
            for (int r = 0; r < 4; ++r) {
                float v = accV[i][r] + vb;
                float u = accU[i][r] + ub;
                part[i][r] = w * fast_tanh(v) * fast_sigmoid(u);
            }
        #pragma unroll
        for (int off = 1; off < 16; off <<= 1)
            #pragma unroll
            for (int i = 0; i < 2; ++i)
                #pragma unroll
                for (int r = 0; r < 4; ++r)
                    part[i][r] += __shfl_xor(part[i][r], off);
        if (l15 == 0) {
            #pragma unroll
            for (int i = 0; i < 2; ++i)
                #pragma unroll
                for (int r = 0; r < 4; ++r)
                    sred[wc][i * 16 + kgrp * 4 + r] = part[i][r];
        }
    }
    __syncthreads();
    if (t < BM) {
        float s = sred[0][t];
        #pragma unroll
        for (int w8 = 1; w8 < 8; ++w8) s += sred[w8][t];
        srow[t] = s;
    }
    __syncthreads();

    // ---- wave-parallel per-segment softmax partials ----
    const int gl = index[rb];
    const int gh = index[rb + BM - 1];
    for (int g = gl + wc; g <= gh; g += 8) {
        const int r0 = max(start[g], rb), r1 = min(start[g + 1], rb + BM);
        if (r1 <= r0) continue;
        const bool in = (lane >= r0 - rb) && (lane < r1 - rb);
        float m = in ? srow[lane] : NEG_INIT;
        #pragma unroll
        for (int off = 32; off; off >>= 1) m = fmaxf(m, __shfl_xor(m, off));
        float e = in ? __expf(srow[lane] - m) : 0.f;
        if (in) evals[lane] = e;
        float s = e;
        #pragma unroll
        for (int off = 32; off; off >>= 1) s += __shfl_xor(s, off);
        if (lane == 0) {
            float* slot = P + (size_t)(blk + g) * PS;
            slot[0] = m; slot[1] = s;
        }
    }
    __syncthreads();

    // ---- pooling partials, 2 cols/thread (threads 0..255) ----
    if (t < 256) {
        const int c0 = t * 2;
        for (int g = gl; g <= gh; ++g) {
            const int r0 = max(start[g], rb), r1 = min(start[g + 1], rb + BM);
            if (r1 <= r0) continue;
            float a0 = 0.f, a1 = 0.f;
            for (int r = r0; r < r1; ++r) {
                const int rr = r - rb;
                const float e = evals[rr];
                f16x2 hp = *(const f16x2*)&Xh[rr][c0];                        // b32
                unsigned int rv = *(const unsigned short*)&Xr8[rr * LDRB + c0]; // u16
                float x0 = fmaf(unpack_fp8<0>(rv), RISC, (float)hp[0]);
                float x1 = fmaf(unpack_fp8<1>(rv), RISC, (float)hp[1]);
                a0 = fmaf(e, x0, a0);
                a1 = fmaf(e, x1, a1);
            }
            float2 o = {a0, a1};
            *(float2*)(P + (size_t)(blk + g) * PS + 4 + c0) = o;
        }
    }
}

// ---------------------------------------------------------------------------
// k_merge: combine per-block segment partials; one block per group, t = col.
// ---------------------------------------------------------------------------
__global__ __launch_bounds__(512) void k_merge(const float* __restrict__ P,
                                               const int* __restrict__ start,
                                               float* __restrict__ out)
{
    const int g = blockIdx.x, t = threadIdx.x;
    const int s0 = start[g], s1 = start[g + 1];
    if (s0 >= s1) { out[(size_t)g * D + t] = 0.f; return; }
    const int b0 = s0 >> 5, b1 = (s1 - 1) >> 5;   // BM = 32
    float M = NEG_INIT;
    for (int b = b0; b <= b1; ++b)
        M = fmaxf(M, P[(size_t)(b + g) * PS]);
    float den = 0.f, acc = 0.f;
    for (int b = b0; b <= b1; ++b) {
        const float* slot = P + (size_t)(b + g) * PS;
        float w = __expf(slot[0] - M);
        den += w * slot[1];
        acc += w * slot[4 + t];
    }
    out[(size_t)g * D + t] = acc / (den + 1e-8f);
}

// ---------------------------------------------------------------------------
extern "C" void kernel_launch(void* const* d_in, const int* in_sizes, int n_in,
                              void* d_out, int out_size, void* d_ws, size_t ws_size,
                              hipStream_t stream) {
    const float* feats = (const float*)d_in[0];
    const int*   index = (const int*)d_in[1];
    const float* Vw = (const float*)d_in[3];
    const float* Vb = (const float*)d_in[4];
    const float* Uw = (const float*)d_in[5];
    const float* Ub = (const float*)d_in[6];
    const float* ww = (const float*)d_in[7];
    float* out = (float*)d_out;

    const int N = in_sizes[1];          // 262144
    const int G = out_size / D;         // 512
    const int nblk = (N + BM - 1) / BM; // 8192

    // ws: Wfrag fp16[256*512] | start[G+1] | (16B align) | P[(nblk+G)*PS]
    _Float16* Wfrag = (_Float16*)d_ws;
    int* start      = (int*)(Wfrag + (size_t)256 * 512);
    size_t off      = (size_t)256 * 512 * 2 + (G + 1) * 4;
    off             = (off + 15) & ~(size_t)15;
    float* P        = (float*)((char*)d_ws + off);

    hipLaunchKernelGGL(k_wprep, dim3(256), dim3(64), 0, stream, Vw, Uw, Wfrag);
    hipLaunchKernelGGL(k_bounds, dim3((G + 1 + 255) / 256), dim3(256), 0, stream,
                       index, N, G, start);
    hipLaunchKernelGGL(k_fused, dim3(nblk), dim3(512), 0, stream,
                       feats, Wfrag, Vb, Ub, ww, index, start, P, N);
    hipLaunchKernelGGL(k_merge, dim3(G), dim3(512), 0, stream, P, start, out);
}

// Round 16
// 206.229 us; speedup vs baseline: 1.4678x; 1.0271x over previous
//
#include <hip/hip_runtime.h>
#include <hip/hip_fp8.h>
#include <cstddef>

#define NEG_INIT -1.0e9f

typedef _Float16 f16x8 __attribute__((ext_vector_type(8)));
typedef _Float16 f16x4 __attribute__((ext_vector_type(4)));
typedef _Float16 f16x2 __attribute__((ext_vector_type(2)));
typedef float f32x4 __attribute__((ext_vector_type(4)));

constexpr int D   = 512;   // feature dim
constexpr int BM  = 32;    // rows per block
constexpr int BK  = 32;    // K per MFMA step
constexpr int NKS = D / BK;   // 16
constexpr int SSK = 4;     // K-steps per super-step (128 cols)
constexpr int NSS = NKS / SSK; // 4 super-steps
constexpr int LDH  = 520;  // fp16 row stride (1040 B)
constexpr int LDRB = 520;  // fp8 residual row stride BYTES (%8==0 for b64 writes)
constexpr int PS  = 516;   // partial slot stride (floats): [m, s, pad, pad, f[512]]
constexpr float RSC  = 2048.f;      // residual scale into fp8 range
constexpr float RISC = 1.f / 2048.f;

// lgkm-only barrier: LDS producer/consumer safety WITHOUT draining vmcnt --
// in-flight global prefetches survive across it (counted-vmcnt pattern, T4).
#define BAR_LGKM()                                            \
    do {                                                      \
        asm volatile("s_waitcnt lgkmcnt(0)" ::: "memory");    \
        __builtin_amdgcn_s_barrier();                         \
        asm volatile("" ::: "memory");                        \
    } while (0)

// hardware fp8 convert if available (gfx950), else HIP library path
#if __has_builtin(__builtin_amdgcn_cvt_pk_fp8_f32) && __has_builtin(__builtin_amdgcn_cvt_f32_fp8)
#define HW_FP8 1
#else
#define HW_FP8 0
#endif

__device__ __forceinline__ unsigned int pack_fp8x4(float r0, float r1,
                                                   float r2, float r3) {
#if HW_FP8
    int p = __builtin_amdgcn_cvt_pk_fp8_f32(r0, r1, 0, false);   // bytes 0,1
    p     = __builtin_amdgcn_cvt_pk_fp8_f32(r2, r3, p, true);    // bytes 2,3
    return (unsigned int)p;
#else
    __hip_fp8_e4m3 q0(r0), q1(r1), q2(r2), q3(r3);
    return (unsigned int)q0.__x | ((unsigned int)q1.__x << 8) |
           ((unsigned int)q2.__x << 16) | ((unsigned int)q3.__x << 24);
#endif
}

template <int SEL>
__device__ __forceinline__ float unpack_fp8(unsigned int word) {
#if HW_FP8
    return __builtin_amdgcn_cvt_f32_fp8((int)word, SEL);
#else
    __hip_fp8_e4m3 q;
    q.__x = (unsigned char)(word >> (8 * SEL));
    return (float)q;
#endif
}

// fast gates: v_exp_f32 + v_rcp_f32, inf-safe at both tails, err ~1e-6
__device__ __forceinline__ float fast_tanh(float v) {
    float e2 = __expf(2.f * v);                       // +inf / 0 both safe
    return 1.f - 2.f * __builtin_amdgcn_rcpf(e2 + 1.f);
}
__device__ __forceinline__ float fast_sigmoid(float u) {
    return __builtin_amdgcn_rcpf(1.f + __expf(-u));
}

// ---------------------------------------------------------------------------
// k_wprep: fragment-major fp16 weights.
// ---------------------------------------------------------------------------
__global__ __launch_bounds__(64) void k_wprep(const float* __restrict__ Vw,
                                              const float* __restrict__ Uw,
                                              _Float16* __restrict__ Wfrag) {
    const int bid  = blockIdx.x;
    const int lane = threadIdx.x;
    const int j    = bid & 3;
    const int ks   = (bid >> 2) & 15;
    const int wc   = bid >> 6;
    const int l15  = lane & 15;
    const int kgrp = lane >> 4;
    const float* src = (j < 2 ? Vw + (size_t)(wc * 32 + j * 16 + l15) * D
                              : Uw + (size_t)(wc * 32 + (j - 2) * 16 + l15) * D)
                       + ks * BK + kgrp * 8;
    f16x8 h;
    #pragma unroll
    for (int e = 0; e < 8; ++e) h[e] = (_Float16)src[e];
    *(f16x8*)(Wfrag + ((size_t)bid * 64 + lane) * 8) = h;
}

// ---------------------------------------------------------------------------
// k_bounds: start[g] = lower_bound(index, g), g in [0, G].
// ---------------------------------------------------------------------------
__global__ __launch_bounds__(256) void k_bounds(const int* __restrict__ index,
                                                int N, int G,
                                                int* __restrict__ start) {
    int g = blockIdx.x * blockDim.x + threadIdx.x;
    if (g > G) return;
    int lo = 0, hi = N;
    while (lo < hi) {
        int mid = (lo + hi) >> 1;
        if (index[mid] < g) lo = mid + 1; else hi = mid;
    }
    start[g] = lo;
}

// ---------------------------------------------------------------------------
// k_fused (R9, best measured 206.9 us): 32-row block, 512 threads (8 waves),
// 3 blocks/CU (LDS 50.0 KB).
// SUPER-STEP PIPELINE: K-loop split into 4 super-steps of 4 K-slices.
// At super-step s: issue global loads for s+2 (2x float4/thread), compute
// s's 16 MFMA (Xh ds_reads + L2-resident Wfrag), commit s+1 (cvt -> fp16 Xh
// + fp8 residual Xr8 ds_writes), lgkm-only barrier. The 32x512 fp32 stage
// hides UNDER the K-loop; vmcnt stays outstanding across barriers.
// feats is read from HBM exactly ONCE.
// ---------------------------------------------------------------------------
__global__ __launch_bounds__(512, 6) void k_fused(
    const float* __restrict__ feats, const _Float16* __restrict__ Wfrag,
    const float* __restrict__ Vb, const float* __restrict__ Ub,
    const float* __restrict__ ww, const int* __restrict__ index,
    const int* __restrict__ start, float* __restrict__ P, int N)
{
    __shared__ __align__(16) _Float16 Xh[BM][LDH];         // 33280 B fp16 main
    __shared__ __align__(8)  unsigned char Xr8[BM * LDRB]; // 16640 B fp8 residual
    __shared__ float sred[8][BM];                          //  1024 B
    __shared__ float srow[BM];
    __shared__ float evals[BM];

    const int t    = threadIdx.x;
    const int lane = t & 63;
    const int wc   = t >> 6;     // wave 0..7
    const int l15  = lane & 15;
    const int kgrp = lane >> 4;  // 0..3
    const int blk  = blockIdx.x;
    const int rb   = blk * BM;

    // staging map: thread t -> row t>>4, 8-col chunk (t&15)*8 of each 128-col
    // super-step slab. 16 threads x 32B = contiguous 512B per row segment.
    const int srw  = t >> 4;          // 0..31
    const int scol = (t & 15) * 8;    // 0..120
    const float* xg = feats + (size_t)(rb + srw) * D + scol;

    float4 xa[2][2];                  // 2-superstep in-flight ring (16 VGPR)
    auto issueX = [&](int ss) {
        const float* p = xg + ss * 128;
        xa[ss & 1][0] = *(const float4*)p;
        xa[ss & 1][1] = *(const float4*)(p + 4);
    };
    auto commitX = [&](int ss) {
        const int c0 = ss * 128 + scol;
        float v[8];
        v[0] = xa[ss & 1][0].x; v[1] = xa[ss & 1][0].y;
        v[2] = xa[ss & 1][0].z; v[3] = xa[ss & 1][0].w;
        v[4] = xa[ss & 1][1].x; v[5] = xa[ss & 1][1].y;
        v[6] = xa[ss & 1][1].z; v[7] = xa[ss & 1][1].w;
        f16x8 h;
        float res[8];
        #pragma unroll
        for (int e = 0; e < 8; ++e) {
            h[e] = (_Float16)v[e];
            res[e] = (v[e] - (float)h[e]) * RSC;
        }
        unsigned int rp0 = pack_fp8x4(res[0], res[1], res[2], res[3]);
        unsigned int rp1 = pack_fp8x4(res[4], res[5], res[6], res[7]);
        *(f16x8*)&Xh[srw][c0] = h;
        uint2 rw = {rp0, rp1};
        *(uint2*)&Xr8[srw * LDRB + c0] = rw;    // 8B aligned (LDRB%8==0)
    };

    // per-(wc,lane) base into fragment-major weights
    const _Float16* wbV = Wfrag + (size_t)(wc >> 1) * 32768
                                + (size_t)(wc & 1) * 512 + (size_t)lane * 8;
    const _Float16* wbU = wbV + 1024;

    f32x4 accV[2], accU[2];
    #pragma unroll
    for (int i = 0; i < 2; ++i) {
        accV[i] = (f32x4){0.f, 0.f, 0.f, 0.f};
        accU[i] = (f32x4){0.f, 0.f, 0.f, 0.f};
    }

    // ---- pipelined stage + K-loop ----
    issueX(0); issueX(1);
    commitX(0);
    BAR_LGKM();

    #pragma unroll
    for (int ss = 0; ss < NSS; ++ss) {
        if (ss + 2 < NSS) issueX(ss + 2);     // HBM loads 2 super-steps ahead
        #pragma unroll
        for (int k2 = 0; k2 < SSK; ++k2) {
            const int ks = ss * SSK + k2;
            f16x8 bv = *(const f16x8*)(wbV + (size_t)ks * 2048);
            f16x8 bu = *(const f16x8*)(wbU + (size_t)ks * 2048);
            f16x8 ha[2];
            #pragma unroll
            for (int i = 0; i < 2; ++i)
                ha[i] = *(const f16x8*)&Xh[i * 16 + l15][ks * BK + kgrp * 8];
            #pragma unroll
            for (int i = 0; i < 2; ++i) {
                accV[i] = __builtin_amdgcn_mfma_f32_16x16x32_f16(ha[i], bv, accV[i], 0, 0, 0);
                accU[i] = __builtin_amdgcn_mfma_f32_16x16x32_f16(ha[i], bu, accU[i], 0, 0, 0);
            }
        }
        if (ss + 1 < NSS) {
            commitX(ss + 1);                  // counted vmcnt wait on xa only
            BAR_LGKM();
        }
    }

    // ---- gated epilogue -> per-row scores (fast exp/rcp gates) ----
    {
        const int c = wc * 16 + l15;          // attention col 0..127
        const float vb = Vb[c], ub = Ub[c], w = ww[c];
        float part[2][4];
        #pragma unroll
        for (int i = 0; i < 2; ++i)
            #pragma unroll
            for (int r = 0; r < 4; ++r) {
                float v = accV[i][r] + vb;
                float u = accU[i][r] + ub;
                part[i][r] = w * fast_tanh(v) * fast_sigmoid(u);
            }
        #pragma unroll
        for (int off = 1; off < 16; off <<= 1)
            #pragma unroll
            for (int i = 0; i < 2; ++i)
                #pragma unroll
                for (int r = 0; r < 4; ++r)
                    part[i][r] += __shfl_xor(part[i][r], off);
        if (l15 == 0) {
            #pragma unroll
            for (int i = 0; i < 2; ++i)
                #pragma unroll
                for (int r = 0; r < 4; ++r)
                    sred[wc][i * 16 + kgrp * 4 + r] = part[i][r];
        }
    }
    __syncthreads();
    if (t < BM) {
        float s = sred[0][t];
        #pragma unroll
        for (int w8 = 1; w8 < 8; ++w8) s += sred[w8][t];
        srow[t] = s;
    }
    __syncthreads();

    // ---- wave-parallel per-segment softmax partials ----
    const int gl = index[rb];
    const int gh = index[rb + BM - 1];
    for (int g = gl + wc; g <= gh; g += 8) {
        const int r0 = max(start[g], rb), r1 = min(start[g + 1], rb + BM);
        if (r1 <= r0) continue;
        const bool in = (lane >= r0 - rb) && (lane < r1 - rb);
        float m = in ? srow[lane] : NEG_INIT;
        #pragma unroll
        for (int off = 32; off; off >>= 1) m = fmaxf(m, __shfl_xor(m, off));
        float e = in ? expf(srow[lane] - m) : 0.f;
        if (in) evals[lane] = e;
        float s = e;
        #pragma unroll
        for (int off = 32; off; off >>= 1) s += __shfl_xor(s, off);
        if (lane == 0) {
            float* slot = P + (size_t)(blk + g) * PS;
            slot[0] = m; slot[1] = s;
        }
    }
    __syncthreads();

    // ---- pooling partials, 2 cols/thread (threads 0..255) ----
    if (t < 256) {
        const int c0 = t * 2;
        for (int g = gl; g <= gh; ++g) {
            const int r0 = max(start[g], rb), r1 = min(start[g + 1], rb + BM);
            if (r1 <= r0) continue;
            float a0 = 0.f, a1 = 0.f;
            for (int r = r0; r < r1; ++r) {
                const int rr = r - rb;
                const float e = evals[rr];
                f16x2 hp = *(const f16x2*)&Xh[rr][c0];                        // b32
                unsigned int rv = *(const unsigned short*)&Xr8[rr * LDRB + c0]; // u16
                float x0 = fmaf(unpack_fp8<0>(rv), RISC, (float)hp[0]);
                float x1 = fmaf(unpack_fp8<1>(rv), RISC, (float)hp[1]);
                a0 = fmaf(e, x0, a0);
                a1 = fmaf(e, x1, a1);
            }
            float2 o = {a0, a1};
            *(float2*)(P + (size_t)(blk + g) * PS + 4 + c0) = o;
        }
    }
}

// ---------------------------------------------------------------------------
// k_merge: combine per-block segment partials; one block per group, t = col.
// ---------------------------------------------------------------------------
__global__ __launch_bounds__(512) void k_merge(const float* __restrict__ P,
                                               const int* __restrict__ start,
                                               float* __restrict__ out)
{
    const int g = blockIdx.x, t = threadIdx.x;
    const int s0 = start[g], s1 = start[g + 1];
    if (s0 >= s1) { out[(size_t)g * D + t] = 0.f; return; }
    const int b0 = s0 >> 5, b1 = (s1 - 1) >> 5;   // BM = 32
    float M = NEG_INIT;
    for (int b = b0; b <= b1; ++b)
        M = fmaxf(M, P[(size_t)(b + g) * PS]);
    float den = 0.f, acc = 0.f;
    for (int b = b0; b <= b1; ++b) {
        const float* slot = P + (size_t)(b + g) * PS;
        float w = expf(slot[0] - M);
        den += w * slot[1];
        acc += w * slot[4 + t];
    }
    out[(size_t)g * D + t] = acc / (den + 1e-8f);
}

// ---------------------------------------------------------------------------
extern "C" void kernel_launch(void* const* d_in, const int* in_sizes, int n_in,
                              void* d_out, int out_size, void* d_ws, size_t ws_size,
                              hipStream_t stream) {
    const float* feats = (const float*)d_in[0];
    const int*   index = (const int*)d_in[1];
    const float* Vw = (const float*)d_in[3];
    const float* Vb = (const float*)d_in[4];
    const float* Uw = (const float*)d_in[5];
    const float* Ub = (const float*)d_in[6];
    const float* ww = (const float*)d_in[7];
    float* out = (float*)d_out;

    const int N = in_sizes[1];          // 262144
    const int G = out_size / D;         // 512
    const int nblk = (N + BM - 1) / BM; // 8192

    // ws: Wfrag fp16[256*512] | start[G+1] | (16B align) | P[(nblk+G)*PS]
    _Float16* Wfrag = (_Float16*)d_ws;
    int* start      = (int*)(Wfrag + (size_t)256 * 512);
    size_t off      = (size_t)256 * 512 * 2 + (G + 1) * 4;
    off             = (off + 15) & ~(size_t)15;
    float* P        = (float*)((char*)d_ws + off);

    hipLaunchKernelGGL(k_wprep, dim3(256), dim3(64), 0, stream, Vw, Uw, Wfrag);
    hipLaunchKernelGGL(k_bounds, dim3((G + 1 + 255) / 256), dim3(256), 0, stream,
                       index, N, G, start);
    hipLaunchKernelGGL(k_fused, dim3(nblk), dim3(512), 0, stream,
                       feats, Wfrag, Vb, Ub, ww, index, start, P, N);
    hipLaunchKernelGGL(k_merge, dim3(G), dim3(512), 0, stream, P, start, out);
}